// Round 7
// baseline (1499.839 us; speedup 1.0000x reference)
//
#include <hip/hip_runtime.h>
#include <math.h>

#define T_STEPS 8
#define N_NODES 20000
#define F_IN    128
#define H_DIM   256
#define E_EDGES 320000

typedef __attribute__((ext_vector_type(8))) short short8;
typedef __attribute__((ext_vector_type(4))) float f32x4;

__device__ __forceinline__ void split2(float v, unsigned short& h, unsigned short& l) {
    unsigned vi = __float_as_uint(v);
    h = (unsigned short)(vi >> 16);
    float hf = __uint_as_float(vi & 0xffff0000u);
    l = (unsigned short)(__float_as_uint(v - hf) >> 16);
}

// ---------------- CSR build ----------------

__global__ void count_kernel(const int* __restrict__ dst, int* __restrict__ counts, int E) {
    int e = blockIdx.x * blockDim.x + threadIdx.x;
    if (e < E) atomicAdd(&counts[dst[e]], 1);
}

__global__ void scan_kernel(const int* __restrict__ counts, int* __restrict__ row_ptr,
                            int* __restrict__ cursors, int n) {
    __shared__ int buf[1024];
    __shared__ int carry_s;
    int tid = threadIdx.x;
    if (tid == 0) carry_s = 0;
    __syncthreads();
    for (int base = 0; base < n; base += 1024) {
        int i = base + tid;
        int v = (i < n) ? counts[i] : 0;
        buf[tid] = v;
        __syncthreads();
        for (int off = 1; off < 1024; off <<= 1) {
            int t = (tid >= off) ? buf[tid - off] : 0;
            __syncthreads();
            buf[tid] += t;
            __syncthreads();
        }
        int incl = buf[tid];
        int carry = carry_s;
        if (i < n) {
            int ex = carry + incl - v;
            row_ptr[i] = ex;
            cursors[i] = ex;
        }
        __syncthreads();
        if (tid == 1023) carry_s = carry + incl;
        __syncthreads();
    }
    if (tid == 0) row_ptr[n] = carry_s;
}

__global__ void fill_kernel(const int* __restrict__ src, const int* __restrict__ dst,
                            int* __restrict__ cursors, int* __restrict__ col, int E) {
    int e = blockIdx.x * blockDim.x + threadIdx.x;
    if (e < E) {
        int d = dst[e];
        int p = atomicAdd(&cursors[d], 1);
        col[p] = src[e];
    }
}

// ---------------- weight fp32 -> MFMA-fragment-major bf16 hi/lo ----------------
// lane holds B[rt*16 + (lane&15)][kp*32 + (lane>>4)*8 + j], j=0..7
// stored at ((rt*KP32 + kp)*64 + lane)*8 -> one 16B short8 per lane.

__global__ void cvt_frag(const float* __restrict__ W, int K,
                         unsigned short* __restrict__ fh, unsigned short* __restrict__ fl) {
    int g = blockIdx.x * 256 + threadIdx.x;
    int KP32 = K >> 5;
    int total = (H_DIM / 16) * KP32 * 64;
    if (g >= total) return;
    int lane = g & 63;
    int kp = (g >> 6) % KP32;
    int rt = g / (KP32 << 6);
    int r = rt * 16 + (lane & 15);
    int c = kp * 32 + (lane >> 4) * 8;
    const float* p = W + (size_t)r * K + c;
    short8 h, l;
    #pragma unroll
    for (int j = 0; j < 8; ++j) {
        unsigned short hh, ll;
        split2(p[j], hh, ll);
        h[j] = (short)hh; l[j] = (short)ll;
    }
    *(short8*)(fh + (size_t)g * 8) = h;
    *(short8*)(fl + (size_t)g * 8) = l;
}

// ---------------- fused gather + MFMA update ----------------
// Per block: 16 dst rows x 256 cols, 4 waves (each 16x64 = 1 m-tile x 4 n-tiles).
// Grid = 1250 blocks -> ~4.9 blocks/CU (round-6's 625 left the gather phase
// latency-starved at 23% occupancy / 2.2 TB/s vs 3.8 achievable).
// Phase 1: each wave gathers agg for 4 nodes into LDS aggs[16][260], 8 loads
// in flight per lane. Phase 2: register GEMM (A1 fp32 global, A2 LDS),
// weights frag-major bf16 hi/lo, 3-pass split mfma_f32_16x16x32_bf16.
// Ping-pong state buffers outside -> gather of s_prev never races s_new.

__global__ __launch_bounds__(256) void fused_update(
        const float* __restrict__ A1, int K1,
        const float* __restrict__ s_prev,
        const unsigned short* __restrict__ B1h, const unsigned short* __restrict__ B1l,
        const unsigned short* __restrict__ B2h, const unsigned short* __restrict__ B2l,
        float* __restrict__ s_new,
        const int* __restrict__ row_ptr, const int* __restrict__ col,
        const float* __restrict__ leak_ptr, int do_gather) {
    __shared__ float aggs[16][260];
    const int tid = threadIdx.x;
    const int lane = tid & 63, w = tid >> 6;
    const int fr = lane & 15, fq = lane >> 4;
    const int m0 = blockIdx.x * 16;
    const int wn = w * 64;
    const int rtbase = w * 4;

    if (do_gather) {
        const float4* s4 = (const float4*)s_prev;
        #pragma unroll 1
        for (int i = 0; i < 4; ++i) {
            int r = w * 4 + i;
            int beg = row_ptr[m0 + r], end = row_ptr[m0 + r + 1];
            float4 a0 = {0,0,0,0}, a1 = {0,0,0,0}, a2 = {0,0,0,0}, a3 = {0,0,0,0};
            float4 a4 = {0,0,0,0}, a5 = {0,0,0,0}, a6 = {0,0,0,0}, a7 = {0,0,0,0};
            int j = beg;
            for (; j + 7 < end; j += 8) {
                float4 v0 = s4[(size_t)col[j    ] * 64 + lane];
                float4 v1 = s4[(size_t)col[j + 1] * 64 + lane];
                float4 v2 = s4[(size_t)col[j + 2] * 64 + lane];
                float4 v3 = s4[(size_t)col[j + 3] * 64 + lane];
                float4 v4 = s4[(size_t)col[j + 4] * 64 + lane];
                float4 v5 = s4[(size_t)col[j + 5] * 64 + lane];
                float4 v6 = s4[(size_t)col[j + 6] * 64 + lane];
                float4 v7 = s4[(size_t)col[j + 7] * 64 + lane];
                a0.x += v0.x; a0.y += v0.y; a0.z += v0.z; a0.w += v0.w;
                a1.x += v1.x; a1.y += v1.y; a1.z += v1.z; a1.w += v1.w;
                a2.x += v2.x; a2.y += v2.y; a2.z += v2.z; a2.w += v2.w;
                a3.x += v3.x; a3.y += v3.y; a3.z += v3.z; a3.w += v3.w;
                a4.x += v4.x; a4.y += v4.y; a4.z += v4.z; a4.w += v4.w;
                a5.x += v5.x; a5.y += v5.y; a5.z += v5.z; a5.w += v5.w;
                a6.x += v6.x; a6.y += v6.y; a6.z += v6.z; a6.w += v6.w;
                a7.x += v7.x; a7.y += v7.y; a7.z += v7.z; a7.w += v7.w;
            }
            for (; j + 3 < end; j += 4) {
                float4 v0 = s4[(size_t)col[j    ] * 64 + lane];
                float4 v1 = s4[(size_t)col[j + 1] * 64 + lane];
                float4 v2 = s4[(size_t)col[j + 2] * 64 + lane];
                float4 v3 = s4[(size_t)col[j + 3] * 64 + lane];
                a0.x += v0.x; a0.y += v0.y; a0.z += v0.z; a0.w += v0.w;
                a1.x += v1.x; a1.y += v1.y; a1.z += v1.z; a1.w += v1.w;
                a2.x += v2.x; a2.y += v2.y; a2.z += v2.z; a2.w += v2.w;
                a3.x += v3.x; a3.y += v3.y; a3.z += v3.z; a3.w += v3.w;
            }
            for (; j < end; ++j) {
                float4 v = s4[(size_t)col[j] * 64 + lane];
                a0.x += v.x; a0.y += v.y; a0.z += v.z; a0.w += v.w;
            }
            float4 t;
            t.x = ((a0.x + a1.x) + (a2.x + a3.x)) + ((a4.x + a5.x) + (a6.x + a7.x));
            t.y = ((a0.y + a1.y) + (a2.y + a3.y)) + ((a4.y + a5.y) + (a6.y + a7.y));
            t.z = ((a0.z + a1.z) + (a2.z + a3.z)) + ((a4.z + a5.z) + (a6.z + a7.z));
            t.w = ((a0.w + a1.w) + (a2.w + a3.w)) + ((a4.w + a5.w) + (a6.w + a7.w));
            *(float4*)&aggs[r][lane * 4] = t;
        }
        __syncthreads();
    }

    f32x4 acc[4];
    #pragma unroll
    for (int nt = 0; nt < 4; ++nt)
        acc[nt] = (f32x4){0.f, 0.f, 0.f, 0.f};

    // ---- part 1: dense A1 (fp32 global; 16-row slice is L1-resident) ----
    {
        const int KP32 = K1 >> 5;
        #pragma unroll 1
        for (int kp = 0; kp < KP32; ++kp) {
            short8 ah, al;
            {
                const float* ap = A1 + (size_t)(m0 + fr) * K1 + kp * 32 + fq * 8;
                float4 v0 = *(const float4*)ap;
                float4 v1 = *(const float4*)(ap + 4);
                unsigned short h, l;
                split2(v0.x, h, l); ah[0] = (short)h; al[0] = (short)l;
                split2(v0.y, h, l); ah[1] = (short)h; al[1] = (short)l;
                split2(v0.z, h, l); ah[2] = (short)h; al[2] = (short)l;
                split2(v0.w, h, l); ah[3] = (short)h; al[3] = (short)l;
                split2(v1.x, h, l); ah[4] = (short)h; al[4] = (short)l;
                split2(v1.y, h, l); ah[5] = (short)h; al[5] = (short)l;
                split2(v1.z, h, l); ah[6] = (short)h; al[6] = (short)l;
                split2(v1.w, h, l); ah[7] = (short)h; al[7] = (short)l;
            }
            #pragma unroll
            for (int nt = 0; nt < 4; ++nt) {
                size_t off = ((size_t)((rtbase + nt) * KP32 + kp) * 64 + lane) * 8;
                short8 bh = *(const short8*)(B1h + off);
                short8 bl = *(const short8*)(B1l + off);
                f32x4 c = acc[nt];
                c = __builtin_amdgcn_mfma_f32_16x16x32_bf16(ah, bh, c, 0, 0, 0);
                c = __builtin_amdgcn_mfma_f32_16x16x32_bf16(al, bh, c, 0, 0, 0);
                c = __builtin_amdgcn_mfma_f32_16x16x32_bf16(ah, bl, c, 0, 0, 0);
                acc[nt] = c;
            }
        }
    }

    // ---- part 2: A2 = aggs (LDS) ----
    if (B2h) {
        #pragma unroll 1
        for (int kp = 0; kp < 8; ++kp) {
            short8 ah, al;
            {
                const float* ap = &aggs[fr][kp * 32 + fq * 8];
                float4 v0 = *(const float4*)ap;
                float4 v1 = *(const float4*)(ap + 4);
                unsigned short h, l;
                split2(v0.x, h, l); ah[0] = (short)h; al[0] = (short)l;
                split2(v0.y, h, l); ah[1] = (short)h; al[1] = (short)l;
                split2(v0.z, h, l); ah[2] = (short)h; al[2] = (short)l;
                split2(v0.w, h, l); ah[3] = (short)h; al[3] = (short)l;
                split2(v1.x, h, l); ah[4] = (short)h; al[4] = (short)l;
                split2(v1.y, h, l); ah[5] = (short)h; al[5] = (short)l;
                split2(v1.z, h, l); ah[6] = (short)h; al[6] = (short)l;
                split2(v1.w, h, l); ah[7] = (short)h; al[7] = (short)l;
            }
            #pragma unroll
            for (int nt = 0; nt < 4; ++nt) {
                size_t off = ((size_t)((rtbase + nt) * 8 + kp) * 64 + lane) * 8;
                short8 bh = *(const short8*)(B2h + off);
                short8 bl = *(const short8*)(B2l + off);
                f32x4 c = acc[nt];
                c = __builtin_amdgcn_mfma_f32_16x16x32_bf16(ah, bh, c, 0, 0, 0);
                c = __builtin_amdgcn_mfma_f32_16x16x32_bf16(al, bh, c, 0, 0, 0);
                c = __builtin_amdgcn_mfma_f32_16x16x32_bf16(ah, bl, c, 0, 0, 0);
                acc[nt] = c;
            }
        }
    }

    // ---- epilogue: C[m = m0+fq*4+r][n = wn+nt*16+fr] ----
    const float leak = leak_ptr[0], il = 1.0f - leak;
    #pragma unroll
    for (int r = 0; r < 4; ++r) {
        int m = m0 + fq * 4 + r;
        #pragma unroll
        for (int nt = 0; nt < 4; ++nt) {
            int n = wn + nt * 16 + fr;
            size_t idx = (size_t)m * H_DIM + n;
            float old = s_prev[idx];
            float pre = acc[nt][r];
            float e = __expf(2.0f * pre);
            float th = 1.0f - 2.0f / (e + 1.0f);
            s_new[idx] = leak * th + il * old;
        }
    }
}

// ---------------- launch ----------------

extern "C" void kernel_launch(void* const* d_in, const int* in_sizes, int n_in,
                              void* d_out, int out_size, void* d_ws, size_t ws_size,
                              hipStream_t stream) {
    const float* x        = (const float*)d_in[0];
    const int*   edge     = (const int*)d_in[1];
    const float* w_in0    = (const float*)d_in[2];
    const float* w_rec0   = (const float*)d_in[3];
    const float* w_in1    = (const float*)d_in[4];
    const float* w_rec1   = (const float*)d_in[5];
    const float* leak_ptr = (const float*)d_in[6];

    const int* src = edge;
    const int* dst = edge + E_EDGES;

    char* ws = (char*)d_ws;
    size_t off = 0;
    auto alloc = [&](size_t bytes) -> char* {
        char* p = ws + off;
        off += (bytes + 255) & ~(size_t)255;
        return p;
    };
    const size_t state_bytes = (size_t)N_NODES * H_DIM * sizeof(float);
    // ping-pong buffers; s1 buffer 0 is d_out (t=7 writes buffer (7+1)&1 = 0)
    float* s0b[2]; float* s1b[2];
    s0b[0] = (float*)alloc(state_bytes);
    s0b[1] = (float*)alloc(state_bytes);
    s1b[0] = (float*)d_out;
    s1b[1] = (float*)alloc(state_bytes);
    unsigned short* w0h  = (unsigned short*)alloc(256 * 128 * 2);
    unsigned short* w0l  = (unsigned short*)alloc(256 * 128 * 2);
    unsigned short* wr0h = (unsigned short*)alloc(256 * 256 * 2);
    unsigned short* wr0l = (unsigned short*)alloc(256 * 256 * 2);
    unsigned short* w1h  = (unsigned short*)alloc(256 * 256 * 2);
    unsigned short* w1l  = (unsigned short*)alloc(256 * 256 * 2);
    unsigned short* wr1h = (unsigned short*)alloc(256 * 256 * 2);
    unsigned short* wr1l = (unsigned short*)alloc(256 * 256 * 2);
    int* row_ptr = (int*)alloc((N_NODES + 1) * sizeof(int));
    int* cursors = (int*)alloc(N_NODES * sizeof(int));
    int* counts  = (int*)alloc(N_NODES * sizeof(int));
    int* col     = (int*)alloc((size_t)E_EDGES * sizeof(int));

    hipMemsetAsync(s0b[0], 0, state_bytes, stream);
    hipMemsetAsync(s1b[0], 0, state_bytes, stream);
    hipMemsetAsync(counts, 0, N_NODES * sizeof(int), stream);

    cvt_frag<<<16, 256, 0, stream>>>(w_in0, F_IN, w0h, w0l);
    cvt_frag<<<32, 256, 0, stream>>>(w_rec0, H_DIM, wr0h, wr0l);
    cvt_frag<<<32, 256, 0, stream>>>(w_in1, H_DIM, w1h, w1l);
    cvt_frag<<<32, 256, 0, stream>>>(w_rec1, H_DIM, wr1h, wr1l);

    count_kernel<<<(E_EDGES + 255) / 256, 256, 0, stream>>>(dst, counts, E_EDGES);
    scan_kernel<<<1, 1024, 0, stream>>>(counts, row_ptr, cursors, N_NODES);
    fill_kernel<<<(E_EDGES + 255) / 256, 256, 0, stream>>>(src, dst, cursors, col, E_EDGES);

    dim3 ugrid(N_NODES / 16);            // 20000 = 1250*16 exact

    for (int t = 0; t < T_STEPS; ++t) {
        const float* xt = x + (size_t)t * N_NODES * F_IN;
        int rd = t & 1, wr = rd ^ 1;
        int dg = (t > 0) ? 1 : 0;
        fused_update<<<ugrid, 256, 0, stream>>>(
            xt, F_IN, s0b[rd],
            w0h, w0l, dg ? wr0h : nullptr, dg ? wr0l : nullptr,
            s0b[wr], row_ptr, col, leak_ptr, dg);
        fused_update<<<ugrid, 256, 0, stream>>>(
            s0b[wr], H_DIM, s1b[rd],
            w1h, w1l, dg ? wr1h : nullptr, dg ? wr1l : nullptr,
            s1b[wr], row_ptr, col, leak_ptr, dg);
    }
}

// Round 8
// 1171.690 us; speedup vs baseline: 1.2801x; 1.2801x over previous
//
#include <hip/hip_runtime.h>
#include <math.h>

#define T_STEPS 8
#define N_NODES 20000
#define F_IN    128
#define H_DIM   256
#define E_EDGES 320000

typedef __attribute__((ext_vector_type(8))) short short8;
typedef __attribute__((ext_vector_type(4))) float f32x4;

__device__ __forceinline__ void split2(float v, unsigned short& h, unsigned short& l) {
    unsigned vi = __float_as_uint(v);
    h = (unsigned short)(vi >> 16);
    float hf = __uint_as_float(vi & 0xffff0000u);
    l = (unsigned short)(__float_as_uint(v - hf) >> 16);
}

// ---------------- CSR build ----------------

__global__ void count_kernel(const int* __restrict__ dst, int* __restrict__ counts, int E) {
    int e = blockIdx.x * blockDim.x + threadIdx.x;
    if (e < E) atomicAdd(&counts[dst[e]], 1);
}

__global__ void scan_kernel(const int* __restrict__ counts, int* __restrict__ row_ptr,
                            int* __restrict__ cursors, int n) {
    __shared__ int buf[1024];
    __shared__ int carry_s;
    int tid = threadIdx.x;
    if (tid == 0) carry_s = 0;
    __syncthreads();
    for (int base = 0; base < n; base += 1024) {
        int i = base + tid;
        int v = (i < n) ? counts[i] : 0;
        buf[tid] = v;
        __syncthreads();
        for (int off = 1; off < 1024; off <<= 1) {
            int t = (tid >= off) ? buf[tid - off] : 0;
            __syncthreads();
            buf[tid] += t;
            __syncthreads();
        }
        int incl = buf[tid];
        int carry = carry_s;
        if (i < n) {
            int ex = carry + incl - v;
            row_ptr[i] = ex;
            cursors[i] = ex;
        }
        __syncthreads();
        if (tid == 1023) carry_s = carry + incl;
        __syncthreads();
    }
    if (tid == 0) row_ptr[n] = carry_s;
}

__global__ void fill_kernel(const int* __restrict__ src, const int* __restrict__ dst,
                            int* __restrict__ cursors, int* __restrict__ col, int E) {
    int e = blockIdx.x * blockDim.x + threadIdx.x;
    if (e < E) {
        int d = dst[e];
        int p = atomicAdd(&cursors[d], 1);
        col[p] = src[e];
    }
}

// ---------------- weight fp32 -> MFMA-fragment-major bf16 hi/lo ----------------
// lane holds B[rt*16 + (lane&15)][kp*32 + (lane>>4)*8 + j], j=0..7
// stored at ((rt*KP32 + kp)*64 + lane)*8 -> one 16B short8 per lane.

__global__ void cvt_frag(const float* __restrict__ W, int K,
                         unsigned short* __restrict__ fh, unsigned short* __restrict__ fl) {
    int g = blockIdx.x * 256 + threadIdx.x;
    int KP32 = K >> 5;
    int total = (H_DIM / 16) * KP32 * 64;
    if (g >= total) return;
    int lane = g & 63;
    int kp = (g >> 6) % KP32;
    int rt = g / (KP32 << 6);
    int r = rt * 16 + (lane & 15);
    int c = kp * 32 + (lane >> 4) * 8;
    const float* p = W + (size_t)r * K + c;
    short8 h, l;
    #pragma unroll
    for (int j = 0; j < 8; ++j) {
        unsigned short hh, ll;
        split2(p[j], hh, ll);
        h[j] = (short)hh; l[j] = (short)ll;
    }
    *(short8*)(fh + (size_t)g * 8) = h;
    *(short8*)(fl + (size_t)g * 8) = l;
}

// ---------------- fused gather + MFMA update ----------------
// Per block: 32 dst rows x 256 cols, 4 waves (each 32x64 = 2 m-tiles x 4 n-tiles).
// Grid 625 (r6 shape: best measured tile economics; r7's 16-row halving doubled
// weight traffic and regressed).
// Phase 1: each wave gathers agg for 8 nodes into LDS aggs[32][260], 8 loads
// in flight per lane (r6 had 4). NO barrier yet.
// Phase 2a: dense-A1 register GEMM (no LDS use) -> overlaps other waves' gather.
// barrier. Phase 2b: A2 = LDS aggs GEMM. Weights frag-major bf16 hi/lo,
// 3-pass split mfma_f32_16x16x32_bf16.
// Ping-pong state buffers outside -> gather of s_prev never races s_new.

__global__ __launch_bounds__(256) void fused_update(
        const float* __restrict__ A1, int K1,
        const float* __restrict__ s_prev,
        const unsigned short* __restrict__ B1h, const unsigned short* __restrict__ B1l,
        const unsigned short* __restrict__ B2h, const unsigned short* __restrict__ B2l,
        float* __restrict__ s_new,
        const int* __restrict__ row_ptr, const int* __restrict__ col,
        const float* __restrict__ leak_ptr, int do_gather) {
    __shared__ float aggs[32][260];
    const int tid = threadIdx.x;
    const int lane = tid & 63, w = tid >> 6;
    const int fr = lane & 15, fq = lane >> 4;
    const int m0 = blockIdx.x * 32;
    const int wn = w * 64;
    const int rtbase = w * 4;

    if (do_gather) {
        const float4* s4 = (const float4*)s_prev;
        #pragma unroll 1
        for (int i = 0; i < 8; ++i) {
            int r = w * 8 + i;
            int beg = row_ptr[m0 + r], end = row_ptr[m0 + r + 1];
            float4 a0 = {0,0,0,0}, a1 = {0,0,0,0}, a2 = {0,0,0,0}, a3 = {0,0,0,0};
            float4 a4 = {0,0,0,0}, a5 = {0,0,0,0}, a6 = {0,0,0,0}, a7 = {0,0,0,0};
            int j = beg;
            for (; j + 7 < end; j += 8) {
                float4 v0 = s4[(size_t)col[j    ] * 64 + lane];
                float4 v1 = s4[(size_t)col[j + 1] * 64 + lane];
                float4 v2 = s4[(size_t)col[j + 2] * 64 + lane];
                float4 v3 = s4[(size_t)col[j + 3] * 64 + lane];
                float4 v4 = s4[(size_t)col[j + 4] * 64 + lane];
                float4 v5 = s4[(size_t)col[j + 5] * 64 + lane];
                float4 v6 = s4[(size_t)col[j + 6] * 64 + lane];
                float4 v7 = s4[(size_t)col[j + 7] * 64 + lane];
                a0.x += v0.x; a0.y += v0.y; a0.z += v0.z; a0.w += v0.w;
                a1.x += v1.x; a1.y += v1.y; a1.z += v1.z; a1.w += v1.w;
                a2.x += v2.x; a2.y += v2.y; a2.z += v2.z; a2.w += v2.w;
                a3.x += v3.x; a3.y += v3.y; a3.z += v3.z; a3.w += v3.w;
                a4.x += v4.x; a4.y += v4.y; a4.z += v4.z; a4.w += v4.w;
                a5.x += v5.x; a5.y += v5.y; a5.z += v5.z; a5.w += v5.w;
                a6.x += v6.x; a6.y += v6.y; a6.z += v6.z; a6.w += v6.w;
                a7.x += v7.x; a7.y += v7.y; a7.z += v7.z; a7.w += v7.w;
            }
            for (; j + 3 < end; j += 4) {
                float4 v0 = s4[(size_t)col[j    ] * 64 + lane];
                float4 v1 = s4[(size_t)col[j + 1] * 64 + lane];
                float4 v2 = s4[(size_t)col[j + 2] * 64 + lane];
                float4 v3 = s4[(size_t)col[j + 3] * 64 + lane];
                a0.x += v0.x; a0.y += v0.y; a0.z += v0.z; a0.w += v0.w;
                a1.x += v1.x; a1.y += v1.y; a1.z += v1.z; a1.w += v1.w;
                a2.x += v2.x; a2.y += v2.y; a2.z += v2.z; a2.w += v2.w;
                a3.x += v3.x; a3.y += v3.y; a3.z += v3.z; a3.w += v3.w;
            }
            for (; j < end; ++j) {
                float4 v = s4[(size_t)col[j] * 64 + lane];
                a0.x += v.x; a0.y += v.y; a0.z += v.z; a0.w += v.w;
            }
            float4 t;
            t.x = ((a0.x + a1.x) + (a2.x + a3.x)) + ((a4.x + a5.x) + (a6.x + a7.x));
            t.y = ((a0.y + a1.y) + (a2.y + a3.y)) + ((a4.y + a5.y) + (a6.y + a7.y));
            t.z = ((a0.z + a1.z) + (a2.z + a3.z)) + ((a4.z + a5.z) + (a6.z + a7.z));
            t.w = ((a0.w + a1.w) + (a2.w + a3.w)) + ((a4.w + a5.w) + (a6.w + a7.w));
            *(float4*)&aggs[r][lane * 4] = t;
        }
        // no barrier here: part-1 GEMM is LDS-independent; barrier before part-2
    }

    f32x4 acc[2][4];
    #pragma unroll
    for (int mi = 0; mi < 2; ++mi)
        #pragma unroll
        for (int nt = 0; nt < 4; ++nt)
            acc[mi][nt] = (f32x4){0.f, 0.f, 0.f, 0.f};

    // ---- part 1: dense A1 (fp32 global) ----
    {
        const int KP32 = K1 >> 5;
        #pragma unroll 1
        for (int kp = 0; kp < KP32; ++kp) {
            short8 ah[2], al[2];
            #pragma unroll
            for (int mi = 0; mi < 2; ++mi) {
                const float* ap = A1 + (size_t)(m0 + mi * 16 + fr) * K1 + kp * 32 + fq * 8;
                float4 v0 = *(const float4*)ap;
                float4 v1 = *(const float4*)(ap + 4);
                unsigned short h, l;
                split2(v0.x, h, l); ah[mi][0] = (short)h; al[mi][0] = (short)l;
                split2(v0.y, h, l); ah[mi][1] = (short)h; al[mi][1] = (short)l;
                split2(v0.z, h, l); ah[mi][2] = (short)h; al[mi][2] = (short)l;
                split2(v0.w, h, l); ah[mi][3] = (short)h; al[mi][3] = (short)l;
                split2(v1.x, h, l); ah[mi][4] = (short)h; al[mi][4] = (short)l;
                split2(v1.y, h, l); ah[mi][5] = (short)h; al[mi][5] = (short)l;
                split2(v1.z, h, l); ah[mi][6] = (short)h; al[mi][6] = (short)l;
                split2(v1.w, h, l); ah[mi][7] = (short)h; al[mi][7] = (short)l;
            }
            short8 bh[4], bl[4];
            #pragma unroll
            for (int nt = 0; nt < 4; ++nt) {
                size_t off = ((size_t)((rtbase + nt) * KP32 + kp) * 64 + lane) * 8;
                bh[nt] = *(const short8*)(B1h + off);
                bl[nt] = *(const short8*)(B1l + off);
            }
            #pragma unroll
            for (int mi = 0; mi < 2; ++mi)
                #pragma unroll
                for (int nt = 0; nt < 4; ++nt) {
                    f32x4 c = acc[mi][nt];
                    c = __builtin_amdgcn_mfma_f32_16x16x32_bf16(ah[mi], bh[nt], c, 0, 0, 0);
                    c = __builtin_amdgcn_mfma_f32_16x16x32_bf16(al[mi], bh[nt], c, 0, 0, 0);
                    c = __builtin_amdgcn_mfma_f32_16x16x32_bf16(ah[mi], bl[nt], c, 0, 0, 0);
                    acc[mi][nt] = c;
                }
        }
    }

    // ---- part 2: A2 = aggs (LDS) ----
    if (B2h) {
        __syncthreads();   // aggs written by all waves must be visible
        #pragma unroll 1
        for (int kp = 0; kp < 8; ++kp) {
            short8 ah[2], al[2];
            #pragma unroll
            for (int mi = 0; mi < 2; ++mi) {
                const float* ap = &aggs[mi * 16 + fr][kp * 32 + fq * 8];
                float4 v0 = *(const float4*)ap;
                float4 v1 = *(const float4*)(ap + 4);
                unsigned short h, l;
                split2(v0.x, h, l); ah[mi][0] = (short)h; al[mi][0] = (short)l;
                split2(v0.y, h, l); ah[mi][1] = (short)h; al[mi][1] = (short)l;
                split2(v0.z, h, l); ah[mi][2] = (short)h; al[mi][2] = (short)l;
                split2(v0.w, h, l); ah[mi][3] = (short)h; al[mi][3] = (short)l;
                split2(v1.x, h, l); ah[mi][4] = (short)h; al[mi][4] = (short)l;
                split2(v1.y, h, l); ah[mi][5] = (short)h; al[mi][5] = (short)l;
                split2(v1.z, h, l); ah[mi][6] = (short)h; al[mi][6] = (short)l;
                split2(v1.w, h, l); ah[mi][7] = (short)h; al[mi][7] = (short)l;
            }
            short8 bh[4], bl[4];
            #pragma unroll
            for (int nt = 0; nt < 4; ++nt) {
                size_t off = ((size_t)((rtbase + nt) * 8 + kp) * 64 + lane) * 8;
                bh[nt] = *(const short8*)(B2h + off);
                bl[nt] = *(const short8*)(B2l + off);
            }
            #pragma unroll
            for (int mi = 0; mi < 2; ++mi)
                #pragma unroll
                for (int nt = 0; nt < 4; ++nt) {
                    f32x4 c = acc[mi][nt];
                    c = __builtin_amdgcn_mfma_f32_16x16x32_bf16(ah[mi], bh[nt], c, 0, 0, 0);
                    c = __builtin_amdgcn_mfma_f32_16x16x32_bf16(al[mi], bh[nt], c, 0, 0, 0);
                    c = __builtin_amdgcn_mfma_f32_16x16x32_bf16(ah[mi], bl[nt], c, 0, 0, 0);
                    acc[mi][nt] = c;
                }
        }
    }

    // ---- epilogue: C[m = m0+mi*16+fq*4+r][n = wn+nt*16+fr] ----
    const float leak = leak_ptr[0], il = 1.0f - leak;
    #pragma unroll
    for (int mi = 0; mi < 2; ++mi)
        #pragma unroll
        for (int r = 0; r < 4; ++r) {
            int m = m0 + mi * 16 + fq * 4 + r;
            #pragma unroll
            for (int nt = 0; nt < 4; ++nt) {
                int n = wn + nt * 16 + fr;
                size_t idx = (size_t)m * H_DIM + n;
                float old = s_prev[idx];
                float pre = acc[mi][nt][r];
                float e = __expf(2.0f * pre);
                float th = 1.0f - 2.0f / (e + 1.0f);
                s_new[idx] = leak * th + il * old;
            }
        }
}

// ---------------- launch ----------------

extern "C" void kernel_launch(void* const* d_in, const int* in_sizes, int n_in,
                              void* d_out, int out_size, void* d_ws, size_t ws_size,
                              hipStream_t stream) {
    const float* x        = (const float*)d_in[0];
    const int*   edge     = (const int*)d_in[1];
    const float* w_in0    = (const float*)d_in[2];
    const float* w_rec0   = (const float*)d_in[3];
    const float* w_in1    = (const float*)d_in[4];
    const float* w_rec1   = (const float*)d_in[5];
    const float* leak_ptr = (const float*)d_in[6];

    const int* src = edge;
    const int* dst = edge + E_EDGES;

    char* ws = (char*)d_ws;
    size_t off = 0;
    auto alloc = [&](size_t bytes) -> char* {
        char* p = ws + off;
        off += (bytes + 255) & ~(size_t)255;
        return p;
    };
    const size_t state_bytes = (size_t)N_NODES * H_DIM * sizeof(float);
    // ping-pong buffers; s1 buffer 0 is d_out (t=7 writes buffer (7+1)&1 = 0)
    float* s0b[2]; float* s1b[2];
    s0b[0] = (float*)alloc(state_bytes);
    s0b[1] = (float*)alloc(state_bytes);
    s1b[0] = (float*)d_out;
    s1b[1] = (float*)alloc(state_bytes);
    unsigned short* w0h  = (unsigned short*)alloc(256 * 128 * 2);
    unsigned short* w0l  = (unsigned short*)alloc(256 * 128 * 2);
    unsigned short* wr0h = (unsigned short*)alloc(256 * 256 * 2);
    unsigned short* wr0l = (unsigned short*)alloc(256 * 256 * 2);
    unsigned short* w1h  = (unsigned short*)alloc(256 * 256 * 2);
    unsigned short* w1l  = (unsigned short*)alloc(256 * 256 * 2);
    unsigned short* wr1h = (unsigned short*)alloc(256 * 256 * 2);
    unsigned short* wr1l = (unsigned short*)alloc(256 * 256 * 2);
    int* row_ptr = (int*)alloc((N_NODES + 1) * sizeof(int));
    int* cursors = (int*)alloc(N_NODES * sizeof(int));
    int* counts  = (int*)alloc(N_NODES * sizeof(int));
    int* col     = (int*)alloc((size_t)E_EDGES * sizeof(int));

    hipMemsetAsync(s0b[0], 0, state_bytes, stream);
    hipMemsetAsync(s1b[0], 0, state_bytes, stream);
    hipMemsetAsync(counts, 0, N_NODES * sizeof(int), stream);

    cvt_frag<<<16, 256, 0, stream>>>(w_in0, F_IN, w0h, w0l);
    cvt_frag<<<32, 256, 0, stream>>>(w_rec0, H_DIM, wr0h, wr0l);
    cvt_frag<<<32, 256, 0, stream>>>(w_in1, H_DIM, w1h, w1l);
    cvt_frag<<<32, 256, 0, stream>>>(w_rec1, H_DIM, wr1h, wr1l);

    count_kernel<<<(E_EDGES + 255) / 256, 256, 0, stream>>>(dst, counts, E_EDGES);
    scan_kernel<<<1, 1024, 0, stream>>>(counts, row_ptr, cursors, N_NODES);
    fill_kernel<<<(E_EDGES + 255) / 256, 256, 0, stream>>>(src, dst, cursors, col, E_EDGES);

    dim3 ugrid(N_NODES / 32);            // 20000 = 625*32 exact

    for (int t = 0; t < T_STEPS; ++t) {
        const float* xt = x + (size_t)t * N_NODES * F_IN;
        int rd = t & 1, wr = rd ^ 1;
        int dg = (t > 0) ? 1 : 0;
        fused_update<<<ugrid, 256, 0, stream>>>(
            xt, F_IN, s0b[rd],
            w0h, w0l, dg ? wr0h : nullptr, dg ? wr0l : nullptr,
            s0b[wr], row_ptr, col, leak_ptr, dg);
        fused_update<<<ugrid, 256, 0, stream>>>(
            s0b[wr], H_DIM, s1b[rd],
            w1h, w1l, dg ? wr1h : nullptr, dg ? wr1l : nullptr,
            s1b[wr], row_ptr, col, leak_ptr, dg);
    }
}